// Round 1
// baseline (2025.648 us; speedup 1.0000x reference)
//
#include <hip/hip_runtime.h>
#include <hip/hip_bf16.h>

typedef _Float16 f16;
typedef __attribute__((ext_vector_type(8))) _Float16 f16x8;  // MFMA A/B frag
typedef __attribute__((ext_vector_type(4))) float f4v;       // MFMA acc

constexpr int NSEQ = 4096;
constexpr int EMB  = 1024;
constexpr int NH   = 16;
constexpr int HD   = 32;       // head dim
constexpr int NL   = 6;
constexpr int HV   = NH * HD;  // 512
constexpr int FF   = 2 * EMB;  // 2048
constexpr int QKVW = 3 * HV;   // 1536 (q|k|v concatenated per row)

// ---------------- embedding: z = table[ctx] + pos; also f16 copy ----------
__global__ __launch_bounds__(256) void embed_kernel(const int* __restrict__ ctx,
    const float* __restrict__ table, const float* __restrict__ pos,
    float* __restrict__ z, f16* __restrict__ zh){
  int t = blockIdx.x * 256 + threadIdx.x;
  int n = t >> 8;
  int e = (t & 255) << 2;
  float4 a = *reinterpret_cast<const float4*>(table + (size_t)ctx[n] * EMB + e);
  float4 b = *reinterpret_cast<const float4*>(pos   + (size_t)n * EMB + e);
  float4 r = {a.x + b.x, a.y + b.y, a.z + b.z, a.w + b.w};
  *reinterpret_cast<float4*>(z + (size_t)n * EMB + e) = r;
  f16 o[4] = {(f16)r.x, (f16)r.y, (f16)r.z, (f16)r.w};
  uint2 u; __builtin_memcpy(&u, o, 8);
  *reinterpret_cast<uint2*>(zh + (size_t)n * EMB + e) = u;
}

// ------------- transpose-convert: out[n*K + k] = (f16)in[k*N + n] ----------
__global__ __launch_bounds__(256) void convT_kernel(const float* __restrict__ in,
    f16* __restrict__ out, int K, int N, long sInZ, long sOutZ){
  __shared__ float t[32][33];
  in  += (size_t)blockIdx.z * sInZ;
  out += (size_t)blockIdx.z * sOutZ;
  int k0 = blockIdx.x * 32, n0 = blockIdx.y * 32;
  int r = threadIdx.x >> 5, c = threadIdx.x & 31;
  #pragma unroll
  for (int i = 0; i < 4; i++)
    t[r + i*8][c] = in[(size_t)(k0 + r + i*8) * N + n0 + c];
  __syncthreads();
  #pragma unroll
  for (int i = 0; i < 4; i++)
    out[(size_t)(n0 + r + i*8) * K + k0 + c] = (f16)t[c][r + i*8];
}

// ---------------- MFMA GEMM: C = act(A @ Bt^T + bias) + res ----------------
// A: f16 [M x K] row-major. Bt: f16 [N x K] row-major (B transposed).
// 128x128 tile, BK=32, 4 waves (2x2 of 64x64). 16x16x32 f16 MFMA.
// C/D: col = lane&15, row = quad*4 + reg   [m89/m91-verified, dtype-indep].
template<typename CT>
__global__ __launch_bounds__(256) void gemm_mfma(
    const f16* __restrict__ A, const f16* __restrict__ Bt, CT* C,
    const float* __restrict__ bias, const float* res,
    int K, int Nc, int leaky)
{
  __shared__ f16 Ash[128][40];   // pad 32->40 (80B): 2-way bank alias = free
  __shared__ f16 Bsh[128][40];
  int tid = threadIdx.x;
  int lane = tid & 63, w = tid >> 6;
  int wm = w & 1, wn = w >> 1;
  int l16 = lane & 15, quad = lane >> 4;
  int row0 = blockIdx.y * 128, col0 = blockIdx.x * 128;

  f4v acc[4][4];
  #pragma unroll
  for (int i = 0; i < 4; i++)
    #pragma unroll
    for (int j = 0; j < 4; j++) acc[i][j] = {0.f, 0.f, 0.f, 0.f};

  int sr = tid >> 1;            // staging row 0..127
  int sc = (tid & 1) * 16;      // f16 col 0 or 16

  for (int k0 = 0; k0 < K; k0 += 32) {
    const uint4* ag = reinterpret_cast<const uint4*>(A  + (size_t)(row0 + sr) * K + k0 + sc);
    const uint4* bg = reinterpret_cast<const uint4*>(Bt + (size_t)(col0 + sr) * K + k0 + sc);
    uint4 a0 = ag[0], a1 = ag[1];
    uint4 b0 = bg[0], b1 = bg[1];
    __syncthreads();                       // prior tile fully consumed
    *reinterpret_cast<uint4*>(&Ash[sr][sc])     = a0;
    *reinterpret_cast<uint4*>(&Ash[sr][sc + 8]) = a1;
    *reinterpret_cast<uint4*>(&Bsh[sr][sc])     = b0;
    *reinterpret_cast<uint4*>(&Bsh[sr][sc + 8]) = b1;
    __syncthreads();
    f16x8 af[4], bf[4];
    #pragma unroll
    for (int mt = 0; mt < 4; mt++)
      af[mt] = *reinterpret_cast<const f16x8*>(&Ash[wm*64 + mt*16 + l16][quad*8]);
    #pragma unroll
    for (int nt = 0; nt < 4; nt++)
      bf[nt] = *reinterpret_cast<const f16x8*>(&Bsh[wn*64 + nt*16 + l16][quad*8]);
    #pragma unroll
    for (int mt = 0; mt < 4; mt++)
      #pragma unroll
      for (int nt = 0; nt < 4; nt++)
        acc[mt][nt] = __builtin_amdgcn_mfma_f32_16x16x32_f16(af[mt], bf[nt], acc[mt][nt], 0, 0, 0);
  }

  #pragma unroll
  for (int mt = 0; mt < 4; mt++) {
    #pragma unroll
    for (int nt = 0; nt < 4; nt++) {
      int ccol = col0 + wn*64 + nt*16 + l16;
      float bv = bias ? bias[ccol] : 0.f;
      #pragma unroll
      for (int reg = 0; reg < 4; reg++) {
        int crow = row0 + wm*64 + mt*16 + quad*4 + reg;
        float v = acc[mt][nt][reg] + bv;
        if (leaky) v = v > 0.f ? v : 0.01f * v;
        if (res)   v += res[(size_t)crow * Nc + ccol];
        if constexpr (sizeof(CT) == 2) C[(size_t)crow * Nc + ccol] = (f16)v;
        else                           C[(size_t)crow * Nc + ccol] = v;
      }
    }
  }
}

// ---------------- MFMA flash attention, transposed-score formulation --------
// qkv: f16 [N][1536] = q|k|v sections, each [H][32]. O: f16 [N][512].
// Block = 64 q x 1 head, 4 waves x 16 q; 128-key tiles.
// S^T = K·Q   (A=K rows from Ks, B=Q frag): col=l16=QUERY, row=key.
//   -> per-lane softmax state (one query per lane): max = fmax tree + 2 shfl,
//      sum lane-local, P-write packs 4 consecutive keys (b64, 2-way free).
// O^T = Vt·P  (A=V^T rows, B=P rows): col=l16=query matches l/m state; no
//   cross-lane epilogue; 4 consecutive dims pack into one 8B store.
__global__ __launch_bounds__(256) void attn_mfma(const f16* __restrict__ qkv,
    f16* __restrict__ O)
{
  __shared__ f16 Ks[128][40];      // [key][dim]   stride 80B  (16B-aligned)
  __shared__ f16 Vt[32][136];      // [dim][key]   stride 272B (16B-aligned)
  __shared__ f16 Ps[4][16][136];   // per-wave P [q][key]
  int tid = threadIdx.x;
  int lane = tid & 63, w = tid >> 6;
  int l16 = lane & 15, quad = lane >> 4;
  int h = blockIdx.y;
  int q0 = blockIdx.x * 64 + w * 16;
  const float sc = 0.17677669529663687f;   // 1/sqrt(32)

  // Q frag (B operand): lane holds Q[q0+l16][quad*8..+7], pre-scaled
  f16x8 qf;
  {
    union { uint4 u; f16 e[8]; } qc;
    qc.u = *reinterpret_cast<const uint4*>(
        qkv + (size_t)(q0 + l16) * QKVW + h * HD + quad * 8);
    #pragma unroll
    for (int i = 0; i < 8; i++) qc.e[i] = (f16)((float)qc.e[i] * sc);
    __builtin_memcpy(&qf, qc.e, 16);
  }

  float m_ = -1e30f, lsum = 0.f;           // per-lane state for query l16
  f4v oaccT[2];
  oaccT[0] = {0.f,0.f,0.f,0.f}; oaccT[1] = {0.f,0.f,0.f,0.f};

  int ksrow = tid >> 1, ksc = (tid & 1) * 16;   // K staging: row, 16-f16 half
  int vkp = tid & 63, vdg = tid >> 6;           // V staging: key pair, dim grp

  for (int kt = 0; kt < NSEQ; kt += 128) {
    const f16* kp0 = qkv + (size_t)(kt + ksrow) * QKVW + HV + h * HD + ksc;
    uint4 ka = *reinterpret_cast<const uint4*>(kp0);
    uint4 kb = *reinterpret_cast<const uint4*>(kp0 + 8);
    const f16* vp0 = qkv + (size_t)(kt + 2 * vkp) * QKVW + 2 * HV + h * HD + vdg * 8;
    uint4 va = *reinterpret_cast<const uint4*>(vp0);
    uint4 vb = *reinterpret_cast<const uint4*>(vp0 + QKVW);
    __syncthreads();                       // prior tile fully consumed
    *reinterpret_cast<uint4*>(&Ks[ksrow][ksc])     = ka;
    *reinterpret_cast<uint4*>(&Ks[ksrow][ksc + 8]) = kb;
    {
      union { uint4 u; f16 e[8]; } c0, c1; c0.u = va; c1.u = vb;
      #pragma unroll
      for (int i = 0; i < 8; i++) {        // pack key pair -> one dword
        f16 pr[2] = {c0.e[i], c1.e[i]};
        unsigned d; __builtin_memcpy(&d, pr, 4);
        *reinterpret_cast<unsigned*>(&Vt[vdg * 8 + i][2 * vkp]) = d;
      }
    }
    __syncthreads();

    // S^T[key][q]: 8 key sub-tiles of 16
    f4v s4[8];
    #pragma unroll
    for (int t = 0; t < 8; t++) {
      f16x8 kf = *reinterpret_cast<const f16x8*>(&Ks[t * 16 + l16][quad * 8]);
      s4[t] = __builtin_amdgcn_mfma_f32_16x16x32_f16(kf, qf, (f4v){0.f,0.f,0.f,0.f}, 0, 0, 0);
    }
    // tile max for this query: lane-local tree + cross-quad (2 shfl)
    float tm = s4[0][0];
    #pragma unroll
    for (int t = 0; t < 8; t++)
      #pragma unroll
      for (int r = 0; r < 4; r++) tm = fmaxf(tm, s4[t][r]);
    tm = fmaxf(tm, __shfl_xor(tm, 16));
    tm = fmaxf(tm, __shfl_xor(tm, 32));
    float mN = fmaxf(m_, tm);
    float corr = __expf(m_ - mN);          // first tile: exp(-huge)=0
    m_ = mN;
    float ls = 0.f;
    #pragma unroll
    for (int t = 0; t < 8; t++) {          // exp + packed P write (4 keys)
      f16 pr[4];
      #pragma unroll
      for (int r = 0; r < 4; r++) {
        float p = __expf(s4[t][r] - mN);
        ls += p;
        pr[r] = (f16)p;
      }
      uint2 d; __builtin_memcpy(&d, pr, 8);
      *reinterpret_cast<uint2*>(&Ps[w][l16][t * 16 + quad * 4]) = d;
    }
    lsum = lsum * corr + ls;
    #pragma unroll
    for (int vt = 0; vt < 2; vt++)
      #pragma unroll
      for (int r = 0; r < 4; r++) oaccT[vt][r] *= corr;
    // O^T += Vt · P  (within-wave LDS dep on Ps: lgkmcnt only, no barrier)
    #pragma unroll
    for (int kc = 0; kc < 4; kc++) {
      f16x8 pf = *reinterpret_cast<const f16x8*>(&Ps[w][l16][kc * 32 + quad * 8]);
      #pragma unroll
      for (int vt = 0; vt < 2; vt++) {
        f16x8 vf = *reinterpret_cast<const f16x8*>(&Vt[vt * 16 + l16][kc * 32 + quad * 8]);
        oaccT[vt] = __builtin_amdgcn_mfma_f32_16x16x32_f16(vf, pf, oaccT[vt], 0, 0, 0);
      }
    }
  }
  // cross-quad sum of l (keys split across quads), then lane-local epilogue
  lsum += __shfl_xor(lsum, 16);
  lsum += __shfl_xor(lsum, 32);
  float inv = 1.f / lsum;
  #pragma unroll
  for (int vt = 0; vt < 2; vt++) {
    f16 ob[4];
    #pragma unroll
    for (int r = 0; r < 4; r++) ob[r] = (f16)(oaccT[vt][r] * inv);
    uint2 u; __builtin_memcpy(&u, ob, 8);
    *reinterpret_cast<uint2*>(
        O + (size_t)(q0 + l16) * HV + h * HD + vt * 16 + quad * 4) = u;
  }
}

// ------------- layernorm (dim 1, ddof=1, no eps) + f16 copy ----------------
__global__ __launch_bounds__(256) void ln_kernel(const float* in, float* out,
                                                 f16* __restrict__ outh){
  __shared__ float sm[8];
  int row = blockIdx.x, tid = threadIdx.x;
  float4 x = reinterpret_cast<const float4*>(in + (size_t)row * EMB)[tid];
  float s = x.x + x.y + x.z + x.w;
  #pragma unroll
  for (int o = 32; o > 0; o >>= 1) s += __shfl_down(s, o);
  int wid = tid >> 6, lane = tid & 63;
  if (lane == 0) sm[wid] = s;
  __syncthreads();
  float mean = (sm[0] + sm[1] + sm[2] + sm[3]) * (1.f / EMB);
  float dx = x.x - mean, dy = x.y - mean, dz = x.z - mean, dw = x.w - mean;
  float qs = dx*dx + dy*dy + dz*dz + dw*dw;
  #pragma unroll
  for (int o = 32; o > 0; o >>= 1) qs += __shfl_down(qs, o);
  if (lane == 0) sm[4 + wid] = qs;
  __syncthreads();
  float var = (sm[4] + sm[5] + sm[6] + sm[7]) * (1.f / (EMB - 1));
  float inv = rsqrtf(var);
  float4 y = {dx * inv, dy * inv, dz * inv, dw * inv};
  reinterpret_cast<float4*>(out + (size_t)row * EMB)[tid] = y;
  f16 o4[4] = {(f16)y.x, (f16)y.y, (f16)y.z, (f16)y.w};
  uint2 u; __builtin_memcpy(&u, o4, 8);
  reinterpret_cast<uint2*>(outh + (size_t)row * EMB)[tid] = u;
}

extern "C" void kernel_launch(void* const* d_in, const int* in_sizes, int n_in,
                              void* d_out, int out_size, void* d_ws, size_t ws_size,
                              hipStream_t stream)
{
  const int*   ctx   = (const int*)d_in[0];
  const float* table = (const float*)d_in[1];
  const float* pos   = (const float*)d_in[2];
  const float* Wq    = (const float*)d_in[3];
  const float* Wk    = (const float*)d_in[4];
  const float* Wv    = (const float*)d_in[5];
  const float* Wo    = (const float*)d_in[6];
  const float* W1    = (const float*)d_in[7];
  const float* b1    = (const float*)d_in[8];
  const float* W2    = (const float*)d_in[9];
  const float* b2    = (const float*)d_in[10];

  float* z = (float*)d_out;                 // residual stream f32 [N][E]

  char* ws = (char*)d_ws;
  const size_t MB = 1u << 20;
  // ws layout (52 MB):
  //  [0,16)   an    f32 [N][E]
  //  [16,24)  anh   f16 [N][E]
  //  [24,32)  zh    f16 [N][E]
  //  [32,44)  qkvh  f16 [N][1536]   } h1h f16 [N][2048] overlaps [32,48)
  //  [44,48)  Oh    f16 [N][512]    }
  //  [48,52)  wbuf  f16 (<=4 MB: qkvT 3MB / WoT 1MB / W1T 4MB / W2T 4MB)
  float* an   = (float*)(ws);
  f16*   anh  = (f16*)  (ws + 16 * MB);
  f16*   zh   = (f16*)  (ws + 24 * MB);
  f16*   qkvh = (f16*)  (ws + 32 * MB);
  f16*   Oh   = (f16*)  (ws + 44 * MB);
  f16*   h1h  = (f16*)  (ws + 32 * MB);
  f16*   wbuf = (f16*)  (ws + 48 * MB);

  embed_kernel<<<NSEQ * EMB / 4 / 256, 256, 0, stream>>>(ctx, table, pos, z, zh);

  for (int l = 0; l < NL; l++) {
    const float* wq  = Wq + (size_t)l * NH * EMB * HD;
    const float* wk  = Wk + (size_t)l * NH * EMB * HD;
    const float* wv  = Wv + (size_t)l * NH * EMB * HD;
    const float* wo  = Wo + (size_t)l * HV * EMB;
    const float* w1  = W1 + (size_t)l * EMB * FF;
    const float* bb1 = b1 + (size_t)l * FF;
    const float* w2  = W2 + (size_t)l * FF * EMB;
    const float* bb2 = b2 + (size_t)l * EMB;

    // qkvT rows: [0,512)=Q, [512,1024)=K, [1024,1536)=V; row = sec*512+h*32+v
    convT_kernel<<<dim3(EMB/32, 1, NH), 256, 0, stream>>>(
        wq, wbuf + (size_t)0 * HV * EMB, EMB, HD, (long)EMB * HD, (long)HD * EMB);
    convT_kernel<<<dim3(EMB/32, 1, NH), 256, 0, stream>>>(
        wk, wbuf + (size_t)1 * HV * EMB, EMB, HD, (long)EMB * HD, (long)HD * EMB);
    convT_kernel<<<dim3(EMB/32, 1, NH), 256, 0, stream>>>(
        wv, wbuf + (size_t)2 * HV * EMB, EMB, HD, (long)EMB * HD, (long)HD * EMB);
    // qkvh[N][1536] = zh @ qkvT^T
    gemm_mfma<f16><<<dim3(QKVW/128, NSEQ/128), 256, 0, stream>>>(
        zh, wbuf, qkvh, nullptr, nullptr, EMB, QKVW, 0);

    attn_mfma<<<dim3(NSEQ/64, NH), 256, 0, stream>>>(qkvh, Oh);

    // z += Oh @ Wo : WoT [1024][512]
    convT_kernel<<<dim3(HV/32, EMB/32, 1), 256, 0, stream>>>(
        wo, wbuf, HV, EMB, 0, 0);
    gemm_mfma<float><<<dim3(EMB/128, NSEQ/128), 256, 0, stream>>>(
        Oh, wbuf, z, nullptr, z, HV, EMB, 0);
    ln_kernel<<<NSEQ, 256, 0, stream>>>(z, an, anh);

    // h1 = leaky(an @ W1 + b1) : W1T [2048][1024]
    convT_kernel<<<dim3(EMB/32, FF/32, 1), 256, 0, stream>>>(
        w1, wbuf, EMB, FF, 0, 0);
    gemm_mfma<f16><<<dim3(FF/128, NSEQ/128), 256, 0, stream>>>(
        anh, wbuf, h1h, bb1, nullptr, EMB, FF, 1);
    // z = h1 @ W2 + b2 + an : W2T [1024][2048]
    convT_kernel<<<dim3(FF/32, EMB/32, 1), 256, 0, stream>>>(
        w2, wbuf, FF, EMB, 0, 0);
    gemm_mfma<float><<<dim3(EMB/128, NSEQ/128), 256, 0, stream>>>(
        h1h, wbuf, z, bb2, an, FF, EMB, 0);
    ln_kernel<<<NSEQ, 256, 0, stream>>>(z, z, zh);
  }
}

// Round 3
// 1962.078 us; speedup vs baseline: 1.0324x; 1.0324x over previous
//
#include <hip/hip_runtime.h>
#include <hip/hip_bf16.h>

typedef _Float16 f16;
typedef __attribute__((ext_vector_type(8))) _Float16 f16x8;  // MFMA A/B frag
typedef __attribute__((ext_vector_type(4))) float f4v;       // MFMA acc

constexpr int NSEQ = 4096;
constexpr int EMB  = 1024;
constexpr int NH   = 16;
constexpr int HD   = 32;       // head dim
constexpr int NL   = 6;
constexpr int HV   = NH * HD;  // 512
constexpr int FF   = 2 * EMB;  // 2048
constexpr int QKVW = 3 * HV;   // 1536 (q|k|v concatenated per row)

// raw barrier: drain LDS ops only; leaves global loads in flight (T14)
#define BARRIER_LGKM() do { \
    asm volatile("s_waitcnt lgkmcnt(0)" ::: "memory"); \
    __builtin_amdgcn_s_barrier(); \
    asm volatile("" ::: "memory"); } while (0)

// direct global->LDS DMA, 16B per lane (dest = uniform base + lane*16)
#define GLDS16(gp, lp) __builtin_amdgcn_global_load_lds( \
    (const __attribute__((address_space(1))) void*)(const void*)(gp), \
    (__attribute__((address_space(3))) void*)(void*)(lp), 16, 0, 0)

// pack two f32 -> 2xf16 (RTZ) as a dword
__device__ __forceinline__ unsigned pk2h(float a, float b) {
  auto h = __builtin_amdgcn_cvt_pkrtz(a, b);   // __fp16 ext_vector(2)
  unsigned d; __builtin_memcpy(&d, &h, 4);
  return d;
}

// ---------------- embedding: z = table[ctx] + pos; also f16 copy ----------
__global__ __launch_bounds__(256) void embed_kernel(const int* __restrict__ ctx,
    const float* __restrict__ table, const float* __restrict__ pos,
    float* __restrict__ z, f16* __restrict__ zh){
  int t = blockIdx.x * 256 + threadIdx.x;
  int n = t >> 8;
  int e = (t & 255) << 2;
  float4 a = *reinterpret_cast<const float4*>(table + (size_t)ctx[n] * EMB + e);
  float4 b = *reinterpret_cast<const float4*>(pos   + (size_t)n * EMB + e);
  float4 r = {a.x + b.x, a.y + b.y, a.z + b.z, a.w + b.w};
  *reinterpret_cast<float4*>(z + (size_t)n * EMB + e) = r;
  f16 o[4] = {(f16)r.x, (f16)r.y, (f16)r.z, (f16)r.w};
  uint2 u; __builtin_memcpy(&u, o, 8);
  *reinterpret_cast<uint2*>(zh + (size_t)n * EMB + e) = u;
}

// ------------- transpose-convert: out[n*K + k] = (f16)in[k*N + n] ----------
__global__ __launch_bounds__(256) void convT_kernel(const float* __restrict__ in,
    f16* __restrict__ out, int K, int N, long sInZ, long sOutZ){
  __shared__ float t[32][33];
  in  += (size_t)blockIdx.z * sInZ;
  out += (size_t)blockIdx.z * sOutZ;
  int k0 = blockIdx.x * 32, n0 = blockIdx.y * 32;
  int r = threadIdx.x >> 5, c = threadIdx.x & 31;
  #pragma unroll
  for (int i = 0; i < 4; i++)
    t[r + i*8][c] = in[(size_t)(k0 + r + i*8) * N + n0 + c];
  __syncthreads();
  #pragma unroll
  for (int i = 0; i < 4; i++)
    out[(size_t)(n0 + r + i*8) * K + k0 + c] = (f16)t[c][r + i*8];
}

// ---------------- MFMA GEMM: C = act(A @ Bt^T + bias) + res ----------------
// A: f16 [M x K] row-major. Bt: f16 [N x K] row-major (B transposed).
// 128x128 tile, BK=32, 4 waves (2x2 of 64x64). 16x16x32 f16 MFMA.
// Staging: global_load_lds width=16, linear [128][32] LDS (m97 structure:
// wave w round i covers rows (w*2+i)*16 + lane/4, col (lane&3)*8; LDS dest
// bytes = (w*2+i)*1024 + lane*16 — matches row*64+col*2 exactly).
template<typename CT>
__global__ __launch_bounds__(256) void gemm_mfma(
    const f16* __restrict__ A, const f16* __restrict__ Bt, CT* C,
    const float* __restrict__ bias, const float* res,
    int K, int Nc, int leaky)
{
  __shared__ f16 Ash[128 * 32];
  __shared__ f16 Bsh[128 * 32];
  int tid = threadIdx.x;
  int lane = tid & 63, w = tid >> 6;
  int wm = w & 1, wn = w >> 1;
  int l16 = lane & 15, quad = lane >> 4;
  int row0 = blockIdx.y * 128, col0 = blockIdx.x * 128;

  f4v acc[4][4];
  #pragma unroll
  for (int i = 0; i < 4; i++)
    #pragma unroll
    for (int j = 0; j < 4; j++) acc[i][j] = {0.f, 0.f, 0.f, 0.f};

  int srow = lane >> 2;          // 0..15
  int scol = (lane & 3) * 8;     // 0/8/16/24
  const f16* gA0 = A  + (size_t)(row0 + w*32      + srow) * K + scol;
  const f16* gA1 = A  + (size_t)(row0 + w*32 + 16 + srow) * K + scol;
  const f16* gB0 = Bt + (size_t)(col0 + w*32      + srow) * K + scol;
  const f16* gB1 = Bt + (size_t)(col0 + w*32 + 16 + srow) * K + scol;
  f16* lA0 = Ash + (w*2    ) * 512;
  f16* lA1 = Ash + (w*2 + 1) * 512;
  f16* lB0 = Bsh + (w*2    ) * 512;
  f16* lB1 = Bsh + (w*2 + 1) * 512;

  for (int k0 = 0; k0 < K; k0 += 32) {
    __syncthreads();                       // prior tile fully consumed
    GLDS16(gA0 + k0, lA0);
    GLDS16(gA1 + k0, lA1);
    GLDS16(gB0 + k0, lB0);
    GLDS16(gB1 + k0, lB1);
    __syncthreads();                       // vmcnt(0) drain: tile resident
    f16x8 af[4], bf[4];
    #pragma unroll
    for (int mt = 0; mt < 4; mt++)
      af[mt] = *reinterpret_cast<const f16x8*>(&Ash[(wm*64 + mt*16 + l16) * 32 + quad*8]);
    #pragma unroll
    for (int nt = 0; nt < 4; nt++)
      bf[nt] = *reinterpret_cast<const f16x8*>(&Bsh[(wn*64 + nt*16 + l16) * 32 + quad*8]);
    #pragma unroll
    for (int mt = 0; mt < 4; mt++)
      #pragma unroll
      for (int nt = 0; nt < 4; nt++)
        acc[mt][nt] = __builtin_amdgcn_mfma_f32_16x16x32_f16(af[mt], bf[nt], acc[mt][nt], 0, 0, 0);
  }

  #pragma unroll
  for (int mt = 0; mt < 4; mt++) {
    #pragma unroll
    for (int nt = 0; nt < 4; nt++) {
      int ccol = col0 + wn*64 + nt*16 + l16;
      float bv = bias ? bias[ccol] : 0.f;
      #pragma unroll
      for (int reg = 0; reg < 4; reg++) {
        int crow = row0 + wm*64 + mt*16 + quad*4 + reg;
        float v = acc[mt][nt][reg] + bv;
        if (leaky) v = v > 0.f ? v : 0.01f * v;
        if (res)   v += res[(size_t)crow * Nc + ccol];
        if constexpr (sizeof(CT) == 2) C[(size_t)crow * Nc + ccol] = (f16)v;
        else                           C[(size_t)crow * Nc + ccol] = v;
      }
    }
  }
}

// ---------------- MFMA flash attention, transposed-score formulation --------
// qkv: f16 [N][1536] = q|k|v sections, each [H][32]. O: f16 [N][512].
// Block = 64 q x 1 head, 4 waves x 16 q; 128-key tiles.
// exp2 domain: Q pre-scaled by (1/sqrt(32))*log2(e); exp(S-m) = exp2(s-m).
// Defer-max: skip rescale when max unchanged (bit-exact, corr would be 1).
// T14: next tile's K/V global loads issued before the compute barrier and
// left in flight (lgkm-only barriers — no vmcnt drain).
__global__ __launch_bounds__(256) void attn_mfma(const f16* __restrict__ qkv,
    f16* __restrict__ O)
{
  __shared__ f16 Ks[128][40];      // [key][dim]   stride 80B  (16B-aligned)
  __shared__ f16 Vt[32][136];      // [dim][key]   stride 272B (16B-aligned)
  __shared__ f16 Ps[4][16][136];   // per-wave P [q][key]
  int tid = threadIdx.x;
  int lane = tid & 63, w = tid >> 6;
  int l16 = lane & 15, quad = lane >> 4;
  int h = blockIdx.y;
  int q0 = blockIdx.x * 64 + w * 16;
  const float sc = 0.17677669529663687f * 1.4426950408889634f; // 1/sqrt(32)*log2e

  // Q frag (B operand): lane holds Q[q0+l16][quad*8..+7], pre-scaled
  f16x8 qf;
  {
    union { uint4 u; f16 e[8]; } qc;
    qc.u = *reinterpret_cast<const uint4*>(
        qkv + (size_t)(q0 + l16) * QKVW + h * HD + quad * 8);
    #pragma unroll
    for (int i = 0; i < 8; i++) qc.e[i] = (f16)((float)qc.e[i] * sc);
    __builtin_memcpy(&qf, qc.e, 16);
  }

  float m_ = -1e30f, lsum = 0.f;           // per-lane state for query l16
  f4v oaccT[2];
  oaccT[0] = {0.f,0.f,0.f,0.f}; oaccT[1] = {0.f,0.f,0.f,0.f};

  int ksrow = tid >> 1, ksc = (tid & 1) * 16;   // K staging: row, 16-f16 half
  int vkp = tid & 63, vdg = tid >> 6;           // V staging: key pair, dim grp

  // prologue: prefetch tile 0
  uint4 ka, kb, va, vb;
  {
    const f16* kp0 = qkv + (size_t)ksrow * QKVW + HV + h * HD + ksc;
    ka = *reinterpret_cast<const uint4*>(kp0);
    kb = *reinterpret_cast<const uint4*>(kp0 + 8);
    const f16* vp0 = qkv + (size_t)(2 * vkp) * QKVW + 2 * HV + h * HD + vdg * 8;
    va = *reinterpret_cast<const uint4*>(vp0);
    vb = *reinterpret_cast<const uint4*>(vp0 + QKVW);
  }

  for (int kt = 0; kt < NSEQ; kt += 128) {
    BARRIER_LGKM();                        // prior tile fully consumed
    *reinterpret_cast<uint4*>(&Ks[ksrow][ksc])     = ka;
    *reinterpret_cast<uint4*>(&Ks[ksrow][ksc + 8]) = kb;
    {
      union { uint4 u; f16 e[8]; } c0, c1; c0.u = va; c1.u = vb;
      #pragma unroll
      for (int i = 0; i < 8; i++) {        // pack key pair -> one dword
        f16 pr[2] = {c0.e[i], c1.e[i]};
        unsigned d; __builtin_memcpy(&d, pr, 4);
        *reinterpret_cast<unsigned*>(&Vt[vdg * 8 + i][2 * vkp]) = d;
      }
    }
    {                                      // T14: prefetch next tile now
      int ktn = (kt + 128) & (NSEQ - 1);
      const f16* kp0 = qkv + (size_t)(ktn + ksrow) * QKVW + HV + h * HD + ksc;
      ka = *reinterpret_cast<const uint4*>(kp0);
      kb = *reinterpret_cast<const uint4*>(kp0 + 8);
      const f16* vp0 = qkv + (size_t)(ktn + 2 * vkp) * QKVW + 2 * HV + h * HD + vdg * 8;
      va = *reinterpret_cast<const uint4*>(vp0);
      vb = *reinterpret_cast<const uint4*>(vp0 + QKVW);
    }
    BARRIER_LGKM();                        // LDS writes visible; loads in flight

    // S^T[key][q]: 8 key sub-tiles of 16
    f4v s4[8];
    __builtin_amdgcn_s_setprio(1);
    #pragma unroll
    for (int t = 0; t < 8; t++) {
      f16x8 kf = *reinterpret_cast<const f16x8*>(&Ks[t * 16 + l16][quad * 8]);
      s4[t] = __builtin_amdgcn_mfma_f32_16x16x32_f16(kf, qf, (f4v){0.f,0.f,0.f,0.f}, 0, 0, 0);
    }
    __builtin_amdgcn_s_setprio(0);

    // tile max: max3-friendly tree + cross-quad (2 shfl)
    float tmt[8];
    #pragma unroll
    for (int t = 0; t < 8; t++)
      tmt[t] = fmaxf(fmaxf(fmaxf(s4[t][0], s4[t][1]), s4[t][2]), s4[t][3]);
    float m01 = fmaxf(tmt[0], tmt[1]), m23 = fmaxf(tmt[2], tmt[3]);
    float m45 = fmaxf(tmt[4], tmt[5]), m67 = fmaxf(tmt[6], tmt[7]);
    float tm = fmaxf(fmaxf(m01, m23), fmaxf(m45, m67));
    tm = fmaxf(tm, __shfl_xor(tm, 16));
    tm = fmaxf(tm, __shfl_xor(tm, 32));
    if (!__all(tm <= m_)) {                // defer-max: skip is bit-exact
      float mN = fmaxf(m_, tm);
      float corr = __builtin_amdgcn_exp2f(m_ - mN);   // first tile: 0
      m_ = mN;
      lsum *= corr;
      #pragma unroll
      for (int vt = 0; vt < 2; vt++)
        #pragma unroll
        for (int r = 0; r < 4; r++) oaccT[vt][r] *= corr;
    }
    float ls = 0.f;
    #pragma unroll
    for (int t = 0; t < 8; t++) {          // exp2 + packed P write (4 keys)
      float p0 = __builtin_amdgcn_exp2f(s4[t][0] - m_);
      float p1 = __builtin_amdgcn_exp2f(s4[t][1] - m_);
      float p2 = __builtin_amdgcn_exp2f(s4[t][2] - m_);
      float p3 = __builtin_amdgcn_exp2f(s4[t][3] - m_);
      ls += (p0 + p1) + (p2 + p3);
      uint2 d;
      d.x = pk2h(p0, p1);
      d.y = pk2h(p2, p3);
      *reinterpret_cast<uint2*>(&Ps[w][l16][t * 16 + quad * 4]) = d;
    }
    lsum += ls;
    // O^T += Vt · P  (within-wave LDS dep on Ps: lgkmcnt only, no barrier)
    __builtin_amdgcn_s_setprio(1);
    #pragma unroll
    for (int kc = 0; kc < 4; kc++) {
      f16x8 pf = *reinterpret_cast<const f16x8*>(&Ps[w][l16][kc * 32 + quad * 8]);
      #pragma unroll
      for (int vt = 0; vt < 2; vt++) {
        f16x8 vf = *reinterpret_cast<const f16x8*>(&Vt[vt * 16 + l16][kc * 32 + quad * 8]);
        oaccT[vt] = __builtin_amdgcn_mfma_f32_16x16x32_f16(vf, pf, oaccT[vt], 0, 0, 0);
      }
    }
    __builtin_amdgcn_s_setprio(0);
  }
  // cross-quad sum of l (keys split across quads), then lane-local epilogue
  lsum += __shfl_xor(lsum, 16);
  lsum += __shfl_xor(lsum, 32);
  float inv = 1.f / lsum;
  #pragma unroll
  for (int vt = 0; vt < 2; vt++) {
    f16 ob[4];
    #pragma unroll
    for (int r = 0; r < 4; r++) ob[r] = (f16)(oaccT[vt][r] * inv);
    uint2 u; __builtin_memcpy(&u, ob, 8);
    *reinterpret_cast<uint2*>(
        O + (size_t)(q0 + l16) * HV + h * HD + vt * 16 + quad * 4) = u;
  }
}

// ------------- layernorm (dim 1, ddof=1, no eps) + f16 copy ----------------
__global__ __launch_bounds__(256) void ln_kernel(const float* in, float* out,
                                                 f16* __restrict__ outh){
  __shared__ float sm[8];
  int row = blockIdx.x, tid = threadIdx.x;
  float4 x = reinterpret_cast<const float4*>(in + (size_t)row * EMB)[tid];
  float s = x.x + x.y + x.z + x.w;
  #pragma unroll
  for (int o = 32; o > 0; o >>= 1) s += __shfl_down(s, o);
  int wid = tid >> 6, lane = tid & 63;
  if (lane == 0) sm[wid] = s;
  __syncthreads();
  float mean = (sm[0] + sm[1] + sm[2] + sm[3]) * (1.f / EMB);
  float dx = x.x - mean, dy = x.y - mean, dz = x.z - mean, dw = x.w - mean;
  float qs = dx*dx + dy*dy + dz*dz + dw*dw;
  #pragma unroll
  for (int o = 32; o > 0; o >>= 1) qs += __shfl_down(qs, o);
  if (lane == 0) sm[4 + wid] = qs;
  __syncthreads();
  float var = (sm[4] + sm[5] + sm[6] + sm[7]) * (1.f / (EMB - 1));
  float inv = rsqrtf(var);
  float4 y = {dx * inv, dy * inv, dz * inv, dw * inv};
  reinterpret_cast<float4*>(out + (size_t)row * EMB)[tid] = y;
  f16 o4[4] = {(f16)y.x, (f16)y.y, (f16)y.z, (f16)y.w};
  uint2 u; __builtin_memcpy(&u, o4, 8);
  reinterpret_cast<uint2*>(outh + (size_t)row * EMB)[tid] = u;
}

extern "C" void kernel_launch(void* const* d_in, const int* in_sizes, int n_in,
                              void* d_out, int out_size, void* d_ws, size_t ws_size,
                              hipStream_t stream)
{
  const int*   ctx   = (const int*)d_in[0];
  const float* table = (const float*)d_in[1];
  const float* pos   = (const float*)d_in[2];
  const float* Wq    = (const float*)d_in[3];
  const float* Wk    = (const float*)d_in[4];
  const float* Wv    = (const float*)d_in[5];
  const float* Wo    = (const float*)d_in[6];
  const float* W1    = (const float*)d_in[7];
  const float* b1    = (const float*)d_in[8];
  const float* W2    = (const float*)d_in[9];
  const float* b2    = (const float*)d_in[10];

  float* z = (float*)d_out;                 // residual stream f32 [N][E]

  char* ws = (char*)d_ws;
  const size_t MB = 1u << 20;
  // ws layout (52 MB):
  //  [0,16)   an    f32 [N][E]
  //  [16,24)  anh   f16 [N][E]
  //  [24,32)  zh    f16 [N][E]
  //  [32,44)  qkvh  f16 [N][1536]   } h1h f16 [N][2048] overlaps [32,48)
  //  [44,48)  Oh    f16 [N][512]    }
  //  [48,52)  wbuf  f16 (<=4 MB: qkvT 3MB / WoT 1MB / W1T 4MB / W2T 4MB)
  float* an   = (float*)(ws);
  f16*   anh  = (f16*)  (ws + 16 * MB);
  f16*   zh   = (f16*)  (ws + 24 * MB);
  f16*   qkvh = (f16*)  (ws + 32 * MB);
  f16*   Oh   = (f16*)  (ws + 44 * MB);
  f16*   h1h  = (f16*)  (ws + 32 * MB);
  f16*   wbuf = (f16*)  (ws + 48 * MB);

  embed_kernel<<<NSEQ * EMB / 4 / 256, 256, 0, stream>>>(ctx, table, pos, z, zh);

  for (int l = 0; l < NL; l++) {
    const float* wq  = Wq + (size_t)l * NH * EMB * HD;
    const float* wk  = Wk + (size_t)l * NH * EMB * HD;
    const float* wv  = Wv + (size_t)l * NH * EMB * HD;
    const float* wo  = Wo + (size_t)l * HV * EMB;
    const float* w1  = W1 + (size_t)l * EMB * FF;
    const float* bb1 = b1 + (size_t)l * FF;
    const float* w2  = W2 + (size_t)l * FF * EMB;
    const float* bb2 = b2 + (size_t)l * EMB;

    // qkvT rows: [0,512)=Q, [512,1024)=K, [1024,1536)=V; row = sec*512+h*32+v
    convT_kernel<<<dim3(EMB/32, 1, NH), 256, 0, stream>>>(
        wq, wbuf + (size_t)0 * HV * EMB, EMB, HD, (long)EMB * HD, (long)HD * EMB);
    convT_kernel<<<dim3(EMB/32, 1, NH), 256, 0, stream>>>(
        wk, wbuf + (size_t)1 * HV * EMB, EMB, HD, (long)EMB * HD, (long)HD * EMB);
    convT_kernel<<<dim3(EMB/32, 1, NH), 256, 0, stream>>>(
        wv, wbuf + (size_t)2 * HV * EMB, EMB, HD, (long)EMB * HD, (long)HD * EMB);
    // qkvh[N][1536] = zh @ qkvT^T
    gemm_mfma<f16><<<dim3(QKVW/128, NSEQ/128), 256, 0, stream>>>(
        zh, wbuf, qkvh, nullptr, nullptr, EMB, QKVW, 0);

    attn_mfma<<<dim3(NSEQ/64, NH), 256, 0, stream>>>(qkvh, Oh);

    // z += Oh @ Wo : WoT [1024][512]
    convT_kernel<<<dim3(HV/32, EMB/32, 1), 256, 0, stream>>>(
        wo, wbuf, HV, EMB, 0, 0);
    gemm_mfma<float><<<dim3(EMB/128, NSEQ/128), 256, 0, stream>>>(
        Oh, wbuf, z, nullptr, z, HV, EMB, 0);
    ln_kernel<<<NSEQ, 256, 0, stream>>>(z, an, anh);

    // h1 = leaky(an @ W1 + b1) : W1T [2048][1024]
    convT_kernel<<<dim3(EMB/32, FF/32, 1), 256, 0, stream>>>(
        w1, wbuf, EMB, FF, 0, 0);
    gemm_mfma<f16><<<dim3(FF/128, NSEQ/128), 256, 0, stream>>>(
        anh, wbuf, h1h, bb1, nullptr, EMB, FF, 1);
    // z = h1 @ W2 + b2 + an : W2T [1024][2048]
    convT_kernel<<<dim3(FF/32, EMB/32, 1), 256, 0, stream>>>(
        w2, wbuf, FF, EMB, 0, 0);
    gemm_mfma<float><<<dim3(EMB/128, NSEQ/128), 256, 0, stream>>>(
        h1h, wbuf, z, bb2, an, FF, EMB, 0);
    ln_kernel<<<NSEQ, 256, 0, stream>>>(z, z, zh);
  }
}